// Round 1
// baseline (983.849 us; speedup 1.0000x reference)
//
#include <hip/hip_runtime.h>
#include <math.h>

#define C_IN  256
#define C_OUT 256
#define HH 32
#define WW 32
#define TT 8

// ---------------------------------------------------------------------------
// Kernel 1: offset conv — om[n][ch][ho][wo], n=16, ch=27, 32x32.
// One thread per output element; x reads coalesced across wo.
// ---------------------------------------------------------------------------
__global__ __launch_bounds__(256) void offset_conv_kernel(
    const float* __restrict__ x, const float* __restrict__ ow,
    const float* __restrict__ ob, float* __restrict__ om)
{
    int flat = blockIdx.x * 256 + threadIdx.x;   // < 16*27*32*32 = 442368
    int wo = flat & 31;
    int ho = (flat >> 5) & 31;
    int r  = flat >> 10;
    int co = r % 27;
    int n  = r / 27;
    int b = n >> 3, ts = n & 7;

    float acc = ob[co];
    const float* xb = x + ((size_t)b * C_IN * TT + ts) * 1024;  // x[b, :, ts, :, :]
    const float* wb = ow + (size_t)co * C_IN * 9;

    for (int c = 0; c < C_IN; ++c) {
        const float* plane = xb + (size_t)c * (TT * 1024);
        const float* wk = wb + c * 9;
        #pragma unroll
        for (int ki = 0; ki < 3; ++ki) {
            int y = ho - 1 + ki;
            if (y < 0 || y >= HH) continue;
            #pragma unroll
            for (int kj = 0; kj < 3; ++kj) {
                int xx = wo - 1 + kj;
                if (xx < 0 || xx >= WW) continue;
                acc = fmaf(wk[ki * 3 + kj], plane[y * 32 + xx], acc);
            }
        }
    }
    om[flat] = acc;
}

// ---------------------------------------------------------------------------
// Kernel 2: fused bilinear sample + contraction.
// Block = (n, ho): 32 positions x 256 out-channels. 256 threads, thread = o.
// Per-c: stage val[9][32] in LDS (double-buffered, 1 barrier/iter), then
// 288 FMAs/thread with broadcast float4 LDS reads.
// ---------------------------------------------------------------------------
__global__ __launch_bounds__(256) void dcn_main_kernel(
    const float* __restrict__ x, const float* __restrict__ w,
    const float* __restrict__ bias, const float* __restrict__ om,
    float* __restrict__ out)
{
    __shared__ float s_bw[4][288];       // bilinear corner weights (mask premul)
    __shared__ int   s_bi[4][288];       // clamped flat plane indices
    __shared__ float s_val[2][9 * 32];   // staged samples, double-buffered

    const int tid = threadIdx.x;
    const int n  = blockIdx.x >> 5;
    const int ho = blockIdx.x & 31;
    const int b = n >> 3, ts = n & 7;

    // ---- precompute per-(k,wo) sampling descriptors --------------------
    for (int s = tid; s < 288; s += 256) {
        int k  = s >> 5;    // 0..8
        int wo = s & 31;
        float dy = om[((n * 27 + 2 * k    ) * 32 + ho) * 32 + wo];
        float dx = om[((n * 27 + 2 * k + 1) * 32 + ho) * 32 + wo];
        float mv = om[((n * 27 + 18 + k   ) * 32 + ho) * 32 + wo];
        float mk = 1.0f / (1.0f + __expf(-mv));

        float py = dy + (float)(ho - 1 + k / 3);
        float px = dx + (float)(wo - 1 + k % 3);
        float y0f = floorf(py), x0f = floorf(px);
        float ty = py - y0f, tx = px - x0f;
        int y0 = (int)y0f, x0 = (int)x0f;
        int y1 = y0 + 1,   x1 = x0 + 1;
        bool vy0 = (y0 >= 0) && (y0 < HH), vy1 = (y1 >= 0) && (y1 < HH);
        bool vx0 = (x0 >= 0) && (x0 < WW), vx1 = (x1 >= 0) && (x1 < WW);
        int cy0 = min(max(y0, 0), HH - 1), cy1 = min(max(y1, 0), HH - 1);
        int cx0 = min(max(x0, 0), WW - 1), cx1 = min(max(x1, 0), WW - 1);

        s_bw[0][s] = (1.f - ty) * (1.f - tx) * mk * (float)(vy0 && vx0);
        s_bw[1][s] = (1.f - ty) * tx         * mk * (float)(vy0 && vx1);
        s_bw[2][s] = ty * (1.f - tx)         * mk * (float)(vy1 && vx0);
        s_bw[3][s] = ty * tx                 * mk * (float)(vy1 && vx1);
        s_bi[0][s] = cy0 * 32 + cx0;
        s_bi[1][s] = cy0 * 32 + cx1;
        s_bi[2][s] = cy1 * 32 + cx0;
        s_bi[3][s] = cy1 * 32 + cx1;
    }
    __syncthreads();

    float acc[32];
    #pragma unroll
    for (int p = 0; p < 32; ++p) acc[p] = 0.f;

    const int o = tid;
    const float* xb   = x + ((size_t)b * C_IN * TT + ts) * 1024;
    const float* wrow = w + (size_t)o * (C_IN * 9);

    for (int c = 0; c < C_IN; ++c) {
        const float* plane = xb + (size_t)c * (TT * 1024);
        float* vbuf = s_val[c & 1];

        // stage 288 bilinear samples (threads 0..31 do two)
        for (int s = tid; s < 288; s += 256) {
            float v = s_bw[0][s] * plane[s_bi[0][s]]
                    + s_bw[1][s] * plane[s_bi[1][s]]
                    + s_bw[2][s] * plane[s_bi[2][s]]
                    + s_bw[3][s] * plane[s_bi[3][s]];
            vbuf[s] = v;
        }
        __syncthreads();
        // Safe single barrier: buffer (c+1)&1 was last read at iter c-1,
        // separated from its next write by this barrier.

        const float* wc = wrow + c * 9;
        #pragma unroll
        for (int k = 0; k < 9; ++k) {
            float wk = wc[k];
            const float4* v4 = (const float4*)&vbuf[k * 32];
            #pragma unroll
            for (int q = 0; q < 8; ++q) {
                float4 v = v4[q];
                acc[q * 4 + 0] = fmaf(wk, v.x, acc[q * 4 + 0]);
                acc[q * 4 + 1] = fmaf(wk, v.y, acc[q * 4 + 1]);
                acc[q * 4 + 2] = fmaf(wk, v.z, acc[q * 4 + 2]);
                acc[q * 4 + 3] = fmaf(wk, v.w, acc[q * 4 + 3]);
            }
        }
    }

    // ---- epilogue: out[b][o][ts][ho][0..31] ----------------------------
    float bv = bias[o];
    float* obase = out + ((size_t)(b * C_OUT + o) * TT + ts) * 1024 + ho * 32;
    #pragma unroll
    for (int q = 0; q < 8; ++q) {
        float4 v;
        v.x = acc[q * 4 + 0] + bv;
        v.y = acc[q * 4 + 1] + bv;
        v.z = acc[q * 4 + 2] + bv;
        v.w = acc[q * 4 + 3] + bv;
        ((float4*)obase)[q] = v;
    }
}

// ---------------------------------------------------------------------------
extern "C" void kernel_launch(void* const* d_in, const int* in_sizes, int n_in,
                              void* d_out, int out_size, void* d_ws, size_t ws_size,
                              hipStream_t stream) {
    const float* x        = (const float*)d_in[0];  // (2,256,8,32,32)
    const float* weight   = (const float*)d_in[1];  // (256,256,1,3,3)
    const float* bias     = (const float*)d_in[2];  // (256,)
    const float* offset_w = (const float*)d_in[3];  // (27,256,3,3)
    const float* offset_b = (const float*)d_in[4];  // (27,)
    float* out = (float*)d_out;
    float* om  = (float*)d_ws;                      // 16*27*32*32 floats = 1.77 MB

    offset_conv_kernel<<<1728, 256, 0, stream>>>(x, offset_w, offset_b, om);
    dcn_main_kernel<<<512, 256, 0, stream>>>(x, weight, bias, om, out);
}

// Round 2
// 298.418 us; speedup vs baseline: 3.2969x; 3.2969x over previous
//
#include <hip/hip_runtime.h>
#include <math.h>

typedef __attribute__((ext_vector_type(4))) float f32x4;
typedef __attribute__((ext_vector_type(8))) short s16x8;

// f32 -> bf16 round-to-nearest-even
__device__ inline unsigned f2bf(float f) {
    unsigned u = __float_as_uint(f);
    u += 0x7FFFu + ((u >> 16) & 1u);
    return u >> 16;
}
__device__ inline float bflo(unsigned u) { return __uint_as_float(u << 16); }
__device__ inline float bfhi(unsigned u) { return __uint_as_float(u & 0xFFFF0000u); }

// ---------------------------------------------------------------------------
// pack_x: x (2,256,8,32,32) f32 -> x_t[n=b*8+ts][y][xcol][c] bf16 (channels-last)
// ---------------------------------------------------------------------------
__global__ __launch_bounds__(256) void pack_x(const float* __restrict__ x,
                                              unsigned* __restrict__ xt32)
{
    __shared__ float tile[256][33];
    const int tid = threadIdx.x;
    const int n = blockIdx.x >> 5, y = blockIdx.x & 31;
    const int b = n >> 3, ts = n & 7;
    const float* src = x + (((size_t)b * 256 * 8) + ts) * 1024 + y * 32;
    #pragma unroll
    for (int rep = 0; rep < 32; ++rep) {
        int c = rep * 8 + (tid >> 5);
        int w = tid & 31;
        tile[c][w] = src[(size_t)c * 8192 + w];   // coalesced read
    }
    __syncthreads();
    unsigned* dst = xt32 + ((size_t)n * 1024 + y * 32) * 128;
    #pragma unroll
    for (int rep = 0; rep < 16; ++rep) {
        int idx = rep * 256 + tid;
        int cp = idx & 127, w = idx >> 7;
        unsigned lo = f2bf(tile[2 * cp][w]);
        unsigned hi = f2bf(tile[2 * cp + 1][w]);
        dst[(size_t)w * 128 + cp] = lo | (hi << 16);   // coalesced write
    }
}

// ---------------------------------------------------------------------------
// pack_w: weight (256,256,1,3,3) -> Wp[t][o][c] bf16
// ---------------------------------------------------------------------------
__global__ __launch_bounds__(256) void pack_w(const float* __restrict__ w,
                                              short* __restrict__ Wp)
{
    int j = blockIdx.x * 256 + threadIdx.x;          // < 9*256*256
    int c = j & 255, o = (j >> 8) & 255, t = j >> 16;
    Wp[j] = (short)f2bf(w[((size_t)o * 256 + c) * 9 + t]);
}

// ---------------------------------------------------------------------------
// pack_ow: offset_w (27,256,3,3) -> Wo[t][m(pad32)][c] bf16, zero-padded
// ---------------------------------------------------------------------------
__global__ __launch_bounds__(256) void pack_ow(const float* __restrict__ ow,
                                               short* __restrict__ Wo)
{
    int j = blockIdx.x * 256 + threadIdx.x;          // < 9*32*256
    int c = j & 255, m = (j >> 8) & 31, t = j >> 13;
    float v = 0.f;
    if (m < 27) v = ow[((size_t)m * 256 + c) * 9 + t];
    Wo[j] = (short)f2bf(v);
}

// ---------------------------------------------------------------------------
// Fused: offset-conv (MFMA) -> descriptors -> sample+GEMM (MFMA).
// Block = (n, ho). 256 threads = 4 waves. wave: nt = w&1 (n-tile), half = w>>1
// (phase1: K-half, phase2: m-half).
// Verified fragment layouts (learn_hip m89/m120):
//   A[m = lane&15][k = (lane>>4)*8 + j] ; B[k][n = lane&15] ; D: col=lane&15,
//   row=(lane>>4)*4+reg.
// ---------------------------------------------------------------------------
__global__ __launch_bounds__(256) void dcn_fused(
    const short* __restrict__ xt, const short* __restrict__ Wp,
    const short* __restrict__ Wo, const float* __restrict__ bias,
    const float* __restrict__ ob, float* __restrict__ out)
{
    __shared__ float s_bw[4][288];
    __shared__ int   s_bi[4][288];
    __shared__ float pom[2][32][33];

    const int tid = threadIdx.x;
    const int n = blockIdx.x >> 5, ho = blockIdx.x & 31;
    const int lane = tid & 63, wv = tid >> 6;
    const int nt = wv & 1, half = wv >> 1;
    const int l15 = lane & 15, quad = lane >> 4;
    const int pos = nt * 16 + l15;                    // wo position
    const short* xn = xt + (size_t)n * (1024 * 256);

    const s16x8 z8 = {0, 0, 0, 0, 0, 0, 0, 0};

    // ---------------- phase 1: offset conv (M=32, K split by `half`) ------
    f32x4 oacc0 = {0, 0, 0, 0}, oacc1 = {0, 0, 0, 0};
    for (int t = 0; t < 9; ++t) {
        int ki = t / 3, kj = t - 3 * ki;
        int y = ho - 1 + ki;
        if (y < 0 || y >= 32) continue;               // wave-uniform
        int xc = pos - 1 + kj;
        bool vx = (xc >= 0) && (xc < 32);
        int xcl = min(max(xc, 0), 31);
        const short* bp  = xn + (y * 32 + xcl) * 256;
        const short* ap0 = Wo + (t * 32 + l15) * 256;
        #pragma unroll
        for (int cc = 0; cc < 4; ++cc) {
            int c = half * 128 + cc * 32 + quad * 8;
            s16x8 bfrag = *(const s16x8*)(bp + c);
            if (!vx) bfrag = z8;
            s16x8 a0 = *(const s16x8*)(ap0 + c);
            s16x8 a1 = *(const s16x8*)(ap0 + 16 * 256 + c);
            oacc0 = __builtin_amdgcn_mfma_f32_16x16x32_bf16(a0, bfrag, oacc0, 0, 0, 0);
            oacc1 = __builtin_amdgcn_mfma_f32_16x16x32_bf16(a1, bfrag, oacc1, 0, 0, 0);
        }
    }
    #pragma unroll
    for (int r = 0; r < 4; ++r) {
        pom[half][quad * 4 + r][pos]      = oacc0[r];
        pom[half][16 + quad * 4 + r][pos] = oacc1[r];
    }
    __syncthreads();

    // ---------------- descriptors (round-1-verified math) -----------------
    for (int s = tid; s < 288; s += 256) {
        int t = s >> 5, wo = s & 31;
        float dy = pom[0][2 * t][wo]     + pom[1][2 * t][wo]     + ob[2 * t];
        float dx = pom[0][2 * t + 1][wo] + pom[1][2 * t + 1][wo] + ob[2 * t + 1];
        float mv = pom[0][18 + t][wo]    + pom[1][18 + t][wo]    + ob[18 + t];
        float mk = 1.0f / (1.0f + __expf(-mv));
        float py = dy + (float)(ho - 1 + t / 3);
        float px = dx + (float)(wo - 1 + t % 3);
        float y0f = floorf(py), x0f = floorf(px);
        float ty = py - y0f, tx = px - x0f;
        int y0 = (int)y0f, x0 = (int)x0f;
        int y1 = y0 + 1, x1 = x0 + 1;
        bool vy0 = (y0 >= 0) && (y0 < 32), vy1 = (y1 >= 0) && (y1 < 32);
        bool vx0 = (x0 >= 0) && (x0 < 32), vx1 = (x1 >= 0) && (x1 < 32);
        int cy0 = min(max(y0, 0), 31), cy1 = min(max(y1, 0), 31);
        int cx0 = min(max(x0, 0), 31), cx1 = min(max(x1, 0), 31);
        s_bw[0][s] = (1.f - ty) * (1.f - tx) * mk * (float)(vy0 && vx0);
        s_bw[1][s] = (1.f - ty) * tx         * mk * (float)(vy0 && vx1);
        s_bw[2][s] = ty * (1.f - tx)         * mk * (float)(vy1 && vx0);
        s_bw[3][s] = ty * tx                 * mk * (float)(vy1 && vx1);
        s_bi[0][s] = (cy0 * 32 + cx0) * 256;
        s_bi[1][s] = (cy0 * 32 + cx1) * 256;
        s_bi[2][s] = (cy1 * 32 + cx0) * 256;
        s_bi[3][s] = (cy1 * 32 + cx1) * 256;
    }
    __syncthreads();

    // ---------------- phase 2: sample + GEMM (no barriers) ----------------
    f32x4 acc[8];
    #pragma unroll
    for (int mt = 0; mt < 8; ++mt) acc[mt] = (f32x4){0, 0, 0, 0};

    for (int c0 = 0; c0 < 256; c0 += 32) {
        const int c = c0 + quad * 8;
        #pragma unroll 3
        for (int t = 0; t < 9; ++t) {
            const int s = t * 32 + pos;
            float w0 = s_bw[0][s], w1 = s_bw[1][s], w2 = s_bw[2][s], w3 = s_bw[3][s];
            const unsigned* g0 = (const unsigned*)(xn + s_bi[0][s] + c);
            const unsigned* g1 = (const unsigned*)(xn + s_bi[1][s] + c);
            const unsigned* g2 = (const unsigned*)(xn + s_bi[2][s] + c);
            const unsigned* g3 = (const unsigned*)(xn + s_bi[3][s] + c);
            uint4 r0 = *(const uint4*)g0;
            uint4 r1 = *(const uint4*)g1;
            uint4 r2 = *(const uint4*)g2;
            uint4 r3 = *(const uint4*)g3;
            const unsigned* p0 = (const unsigned*)&r0;
            const unsigned* p1 = (const unsigned*)&r1;
            const unsigned* p2 = (const unsigned*)&r2;
            const unsigned* p3 = (const unsigned*)&r3;
            union { s16x8 v; unsigned u[4]; } bu;
            #pragma unroll
            for (int d = 0; d < 4; ++d) {
                float lo = w0 * bflo(p0[d]) + w1 * bflo(p1[d])
                         + w2 * bflo(p2[d]) + w3 * bflo(p3[d]);
                float hi = w0 * bfhi(p0[d]) + w1 * bfhi(p1[d])
                         + w2 * bfhi(p2[d]) + w3 * bfhi(p3[d]);
                bu.u[d] = f2bf(lo) | (f2bf(hi) << 16);
            }
            const short* wbase = Wp + (t * 256 + half * 128 + l15) * 256 + c;
            #pragma unroll
            for (int mt = 0; mt < 8; ++mt) {
                s16x8 a = *(const s16x8*)(wbase + mt * 16 * 256);
                acc[mt] = __builtin_amdgcn_mfma_f32_16x16x32_bf16(a, bu.v, acc[mt], 0, 0, 0);
            }
        }
    }

    // ---------------- epilogue ----------------
    const int bb = n >> 3, ts = n & 7;
    #pragma unroll
    for (int mt = 0; mt < 8; ++mt) {
        #pragma unroll
        for (int r = 0; r < 4; ++r) {
            int oc = half * 128 + mt * 16 + quad * 4 + r;
            out[(((size_t)bb * 256 + oc) * 8 + ts) * 1024 + ho * 32 + pos]
                = acc[mt][r] + bias[oc];
        }
    }
}

// ---------------------------------------------------------------------------
extern "C" void kernel_launch(void* const* d_in, const int* in_sizes, int n_in,
                              void* d_out, int out_size, void* d_ws, size_t ws_size,
                              hipStream_t stream) {
    const float* x        = (const float*)d_in[0];
    const float* weight   = (const float*)d_in[1];
    const float* bias     = (const float*)d_in[2];
    const float* offset_w = (const float*)d_in[3];
    const float* offset_b = (const float*)d_in[4];

    short* xt = (short*)d_ws;                         // 16*1024*256 bf16 = 8.39 MB
    short* Wp = xt + (size_t)16 * 1024 * 256;         // 9*256*256 bf16 = 1.18 MB
    short* Wo = Wp + (size_t)9 * 256 * 256;           // 9*32*256 bf16 = 147 KB

    pack_x <<<512,  256, 0, stream>>>(x, (unsigned*)xt);
    pack_w <<<2304, 256, 0, stream>>>(weight, Wp);
    pack_ow<<<288,  256, 0, stream>>>(offset_w, Wo);
    dcn_fused<<<512, 256, 0, stream>>>(xt, Wp, Wo, bias, offset_b, (float*)d_out);
}

// Round 3
// 226.668 us; speedup vs baseline: 4.3405x; 1.3165x over previous
//
#include <hip/hip_runtime.h>
#include <math.h>

typedef __attribute__((ext_vector_type(4))) float f32x4;
typedef __attribute__((ext_vector_type(8))) short s16x8;

__device__ inline unsigned f2bf(float f) {
    unsigned u = __float_as_uint(f);
    u += 0x7FFFu + ((u >> 16) & 1u);
    return u >> 16;
}
__device__ inline float bflo(unsigned u) { return __uint_as_float(u << 16); }
__device__ inline float bfhi(unsigned u) { return __uint_as_float(u & 0xFFFF0000u); }

// ---------------------------------------------------------------------------
// pack_x: x (2,256,8,32,32) f32 -> xt[n][y][x][c] bf16 channels-last
// ---------------------------------------------------------------------------
__global__ __launch_bounds__(256) void pack_x(const float* __restrict__ x,
                                              unsigned* __restrict__ xt32)
{
    __shared__ float tile[256][33];
    const int tid = threadIdx.x;
    const int n = blockIdx.x >> 5, y = blockIdx.x & 31;
    const int b = n >> 3, ts = n & 7;
    const float* src = x + (((size_t)b * 256 * 8) + ts) * 1024 + y * 32;
    #pragma unroll
    for (int rep = 0; rep < 32; ++rep) {
        int c = rep * 8 + (tid >> 5);
        int w = tid & 31;
        tile[c][w] = src[(size_t)c * 8192 + w];
    }
    __syncthreads();
    unsigned* dst = xt32 + ((size_t)n * 1024 + y * 32) * 128;
    #pragma unroll
    for (int rep = 0; rep < 16; ++rep) {
        int idx = rep * 256 + tid;
        int cp = idx & 127, w = idx >> 7;
        unsigned lo = f2bf(tile[2 * cp][w]);
        unsigned hi = f2bf(tile[2 * cp + 1][w]);
        dst[(size_t)w * 128 + cp] = lo | (hi << 16);
    }
}

// ---------------------------------------------------------------------------
// pack_wo: weight -> Wp[t][o][c] bf16 ; offset_w -> Wo[t][m(pad32)][c] bf16
// ---------------------------------------------------------------------------
__global__ __launch_bounds__(256) void pack_wo(const float* __restrict__ w,
                                               const float* __restrict__ ow,
                                               short* __restrict__ Wp,
                                               short* __restrict__ Wo)
{
    int j = blockIdx.x * 256 + threadIdx.x;
    if (j < 9 * 256 * 256) {
        int c = j & 255, o = (j >> 8) & 255, t = j >> 16;
        Wp[j] = (short)f2bf(w[((size_t)o * 256 + c) * 9 + t]);
    } else {
        int k = j - 9 * 256 * 256;            // < 9*32*256
        int c = k & 255, m = (k >> 8) & 31, t = k >> 13;
        float v = 0.f;
        if (m < 27) v = ow[((size_t)m * 256 + c) * 9 + t];
        Wo[k] = (short)f2bf(v);
    }
}

// ---------------------------------------------------------------------------
// offsets_kernel: MFMA offset-conv + descriptor math -> global descW/descI.
// Block = (n, ho), 4 waves: nt = w&1, half = w>>1 (K-half). (round-2 verified)
// ---------------------------------------------------------------------------
__global__ __launch_bounds__(256) void offsets_kernel(
    const short* __restrict__ xt, const short* __restrict__ Wo,
    const float* __restrict__ ob, float4* __restrict__ descW,
    int4* __restrict__ descI)
{
    __shared__ float pom[2][32][33];
    const int tid = threadIdx.x;
    const int n = blockIdx.x >> 5, ho = blockIdx.x & 31;
    const int lane = tid & 63, wv = tid >> 6;
    const int nt = wv & 1, half = wv >> 1;
    const int l15 = lane & 15, quad = lane >> 4;
    const int pos = nt * 16 + l15;
    const short* xn = xt + (size_t)n * (1024 * 256);
    const s16x8 z8 = {0, 0, 0, 0, 0, 0, 0, 0};

    f32x4 oacc0 = {0, 0, 0, 0}, oacc1 = {0, 0, 0, 0};
    for (int t = 0; t < 9; ++t) {
        int ki = t / 3, kj = t - 3 * ki;
        int y = ho - 1 + ki;
        if (y < 0 || y >= 32) continue;
        int xc = pos - 1 + kj;
        bool vx = (xc >= 0) && (xc < 32);
        int xcl = min(max(xc, 0), 31);
        const short* bp  = xn + (y * 32 + xcl) * 256;
        const short* ap0 = Wo + (t * 32 + l15) * 256;
        #pragma unroll
        for (int cc = 0; cc < 4; ++cc) {
            int c = half * 128 + cc * 32 + quad * 8;
            s16x8 bfrag = *(const s16x8*)(bp + c);
            if (!vx) bfrag = z8;
            s16x8 a0 = *(const s16x8*)(ap0 + c);
            s16x8 a1 = *(const s16x8*)(ap0 + 16 * 256 + c);
            oacc0 = __builtin_amdgcn_mfma_f32_16x16x32_bf16(a0, bfrag, oacc0, 0, 0, 0);
            oacc1 = __builtin_amdgcn_mfma_f32_16x16x32_bf16(a1, bfrag, oacc1, 0, 0, 0);
        }
    }
    #pragma unroll
    for (int r = 0; r < 4; ++r) {
        pom[half][quad * 4 + r][pos]      = oacc0[r];
        pom[half][16 + quad * 4 + r][pos] = oacc1[r];
    }
    __syncthreads();

    for (int s = tid; s < 288; s += 256) {
        int t = s >> 5, wo = s & 31;
        float dy = pom[0][2 * t][wo]     + pom[1][2 * t][wo]     + ob[2 * t];
        float dx = pom[0][2 * t + 1][wo] + pom[1][2 * t + 1][wo] + ob[2 * t + 1];
        float mv = pom[0][18 + t][wo]    + pom[1][18 + t][wo]    + ob[18 + t];
        float mk = 1.0f / (1.0f + __expf(-mv));
        float py = dy + (float)(ho - 1 + t / 3);
        float px = dx + (float)(wo - 1 + t % 3);
        float y0f = floorf(py), x0f = floorf(px);
        float ty = py - y0f, tx = px - x0f;
        int y0 = (int)y0f, x0 = (int)x0f;
        int y1 = y0 + 1, x1 = x0 + 1;
        bool vy0 = (y0 >= 0) && (y0 < 32), vy1 = (y1 >= 0) && (y1 < 32);
        bool vx0 = (x0 >= 0) && (x0 < 32), vx1 = (x1 >= 0) && (x1 < 32);
        int cy0 = min(max(y0, 0), 31), cy1 = min(max(y1, 0), 31);
        int cx0 = min(max(x0, 0), 31), cx1 = min(max(x1, 0), 31);
        float b0 = (1.f - ty) * (1.f - tx) * mk * (float)(vy0 && vx0);
        float b1 = (1.f - ty) * tx         * mk * (float)(vy0 && vx1);
        float b2 = ty * (1.f - tx)         * mk * (float)(vy1 && vx0);
        float b3 = ty * tx                 * mk * (float)(vy1 && vx1);
        size_t base = (size_t)(n * 32 + ho) * 288 + s;
        descW[base] = make_float4(b0, b1, b2, b3);
        descI[base] = make_int4((cy0 * 32 + cx0) * 256, (cy0 * 32 + cx1) * 256,
                                (cy1 * 32 + cx0) * 256, (cy1 * 32 + cx1) * 256);
    }
}

// ---------------------------------------------------------------------------
// init_out: out = bias (f32), vectorized. 4096 blocks.
// ---------------------------------------------------------------------------
__global__ __launch_bounds__(256) void init_out(const float* __restrict__ bias,
                                                float4* __restrict__ out)
{
    int i = blockIdx.x * 256 + threadIdx.x;   // < 1048576
    int oc = (i >> 11) & 255;
    float bv = bias[oc];
    out[i] = make_float4(bv, bv, bv, bv);
}

// ---------------------------------------------------------------------------
// dcn_main: block = (n, ho, kh). 4 waves = oc-quarters, each does both
// n-tiles (A-frag reuse). 18 stages of (64 ch, 1 tap): cooperative repack
// -> LDS (each sample repacked once), single-barrier dbuf, 16 MFMA/stage.
// K-partials combined via f32 atomicAdd onto bias-initialized out.
// ---------------------------------------------------------------------------
__global__ __launch_bounds__(256, 4) void dcn_main(
    const short* __restrict__ xt, const short* __restrict__ Wp,
    const float4* __restrict__ descW, const int4* __restrict__ descI,
    float* __restrict__ out)
{
    __shared__ short  sB[2][32 * 72];    // 32 pos x 64 c (+8 pad), 16B-aligned rows
    __shared__ float4 sdw[288];
    __shared__ int4   sdi[288];

    const int tid = threadIdx.x;
    const int bid = blockIdx.x;
    const int kh = bid & 1;
    const int r  = bid >> 1;
    const int n = r >> 5, ho = r & 31;

    // stage descriptors for this (n, ho)
    {
        const float4* dW = descW + (size_t)(n * 32 + ho) * 288;
        const int4*   dI = descI + (size_t)(n * 32 + ho) * 288;
        for (int i = tid; i < 288; i += 256) { sdw[i] = dW[i]; sdi[i] = dI[i]; }
    }
    __syncthreads();

    const int pos = tid & 31, oct = tid >> 5;      // repack role
    const int oq = tid >> 6;                       // wave = oc-quarter
    const int lane = tid & 63, l15 = lane & 15, quad = lane >> 4;
    const short* xn = xt + (size_t)n * (1024 * 256);

    f32x4 acc[8];
    #pragma unroll
    for (int i = 0; i < 8; ++i) acc[i] = (f32x4){0, 0, 0, 0};

    for (int s = 0; s < 18; ++s) {
        const int t = s % 9;
        const int cbase = (kh * 2 + (s / 9)) * 64;

        // ---- cooperative repack: B-tile[32 pos][64 c] -> LDS -------------
        {
            const float4 w4 = sdw[t * 32 + pos];
            const int4   i4 = sdi[t * 32 + pos];
            const int cc = cbase + oct * 8;
            uint4 q0 = *(const uint4*)(xn + i4.x + cc);
            uint4 q1 = *(const uint4*)(xn + i4.y + cc);
            uint4 q2 = *(const uint4*)(xn + i4.z + cc);
            uint4 q3 = *(const uint4*)(xn + i4.w + cc);
            const unsigned* p0 = (const unsigned*)&q0;
            const unsigned* p1 = (const unsigned*)&q1;
            const unsigned* p2 = (const unsigned*)&q2;
            const unsigned* p3 = (const unsigned*)&q3;
            union { s16x8 v; unsigned u[4]; } bu;
            #pragma unroll
            for (int d = 0; d < 4; ++d) {
                float lo = w4.x * bflo(p0[d]) + w4.y * bflo(p1[d])
                         + w4.z * bflo(p2[d]) + w4.w * bflo(p3[d]);
                float hi = w4.x * bfhi(p0[d]) + w4.y * bfhi(p1[d])
                         + w4.z * bfhi(p2[d]) + w4.w * bfhi(p3[d]);
                bu.u[d] = f2bf(lo) | (f2bf(hi) << 16);
            }
            *(s16x8*)&sB[s & 1][pos * 72 + oct * 8] = bu.v;
        }
        __syncthreads();
        // single barrier per stage is safe: buffer b=s&1 written at stage s
        // is next written at s+2, which every wave reaches only after the
        // barrier at s+1, by which time all reads of stage s are complete.

        // ---- A-frags (global, coalesced 16 rows x 64B) + B-frags + MFMA --
        const short* ap = Wp + ((size_t)(t * 256 + oq * 64 + l15)) * 256
                             + cbase + quad * 8;
        s16x8 afr[4][2];
        #pragma unroll
        for (int mt = 0; mt < 4; ++mt)
            #pragma unroll
            for (int kc = 0; kc < 2; ++kc)
                afr[mt][kc] = *(const s16x8*)(ap + mt * 16 * 256 + kc * 32);

        s16x8 bfr[2][2];
        #pragma unroll
        for (int nt = 0; nt < 2; ++nt)
            #pragma unroll
            for (int kc = 0; kc < 2; ++kc)
                bfr[nt][kc] = *(const s16x8*)
                    &sB[s & 1][(nt * 16 + l15) * 72 + kc * 32 + quad * 8];

        #pragma unroll
        for (int mt = 0; mt < 4; ++mt)
            #pragma unroll
            for (int nt = 0; nt < 2; ++nt) {
                acc[mt * 2 + nt] = __builtin_amdgcn_mfma_f32_16x16x32_bf16(
                    afr[mt][0], bfr[nt][0], acc[mt * 2 + nt], 0, 0, 0);
                acc[mt * 2 + nt] = __builtin_amdgcn_mfma_f32_16x16x32_bf16(
                    afr[mt][1], bfr[nt][1], acc[mt * 2 + nt], 0, 0, 0);
            }
    }

    // ---- epilogue: atomic K-reduce onto bias-initialized out -------------
    const int bb = n >> 3, ts = n & 7;
    #pragma unroll
    for (int mt = 0; mt < 4; ++mt)
        #pragma unroll
        for (int nt = 0; nt < 2; ++nt)
            #pragma unroll
            for (int rr = 0; rr < 4; ++rr) {
                int oc = oq * 64 + mt * 16 + quad * 4 + rr;
                int p  = nt * 16 + l15;
                atomicAdd(out + (((size_t)bb * 256 + oc) * 8 + ts) * 1024
                              + ho * 32 + p,
                          acc[mt * 2 + nt][rr]);
            }
}

// ---------------------------------------------------------------------------
extern "C" void kernel_launch(void* const* d_in, const int* in_sizes, int n_in,
                              void* d_out, int out_size, void* d_ws, size_t ws_size,
                              hipStream_t stream) {
    const float* x        = (const float*)d_in[0];
    const float* weight   = (const float*)d_in[1];
    const float* bias     = (const float*)d_in[2];
    const float* offset_w = (const float*)d_in[3];
    const float* offset_b = (const float*)d_in[4];

    char* ws = (char*)d_ws;
    short*  xt    = (short*)ws;                       ws += (size_t)16 * 1024 * 256 * 2; // 8.39 MB
    short*  Wp    = (short*)ws;                       ws += (size_t)9 * 256 * 256 * 2;   // 1.18 MB
    short*  Wo    = (short*)ws;                       ws += (size_t)9 * 32 * 256 * 2;    // 147 KB
    float4* descW = (float4*)ws;                      ws += (size_t)147456 * 16;         // 2.36 MB
    int4*   descI = (int4*)ws;                        ws += (size_t)147456 * 16;         // 2.36 MB

    pack_x        <<<512,  256, 0, stream>>>(x, (unsigned*)xt);
    pack_wo       <<<2592, 256, 0, stream>>>(weight, offset_w, Wp, Wo);
    offsets_kernel<<<512,  256, 0, stream>>>(xt, Wo, offset_b, descW, descI);
    init_out      <<<4096, 256, 0, stream>>>(bias, (float4*)d_out);
    dcn_main      <<<1024, 256, 0, stream>>>(xt, Wp, descW, descI, (float*)d_out);
}